// Round 1
// baseline (364.784 us; speedup 1.0000x reference)
//
#include <hip/hip_runtime.h>
#include <math.h>

#define NN 50000
#define NE 800000
#define DD 128

// ---------------- CSR build ----------------

__global__ __launch_bounds__(256) void k_init(int* __restrict__ cnt) {
    int i = blockIdx.x * 256 + threadIdx.x;
    if (i < NN) cnt[i] = 0;
}

__global__ __launch_bounds__(256) void k_count(const int* __restrict__ dst, int* __restrict__ cnt) {
    int e = blockIdx.x * 256 + threadIdx.x;
    if (e < NE) atomicAdd(&cnt[dst[e]], 1);
}

__global__ __launch_bounds__(256) void k_scan_block(const int* __restrict__ cnt, int* __restrict__ bsum) {
    __shared__ int s[256];
    int tid = threadIdx.x;
    int i = blockIdx.x * 256 + tid;
    int v = (i < NN) ? cnt[i] : 0;
    s[tid] = v;
    __syncthreads();
    for (int o = 128; o > 0; o >>= 1) {
        if (tid < o) s[tid] += s[tid + o];
        __syncthreads();
    }
    if (tid == 0) bsum[blockIdx.x] = s[0];
}

__global__ __launch_bounds__(256) void k_scan_top(int* __restrict__ bsum, int nb) {
    __shared__ int s[256];
    int tid = threadIdx.x;
    int v = (tid < nb) ? bsum[tid] : 0;
    s[tid] = v;
    __syncthreads();
    for (int o = 1; o < 256; o <<= 1) {
        int t = (tid >= o) ? s[tid - o] : 0;
        __syncthreads();
        s[tid] += t;
        __syncthreads();
    }
    if (tid < nb) bsum[tid] = s[tid] - v;  // exclusive
}

__global__ __launch_bounds__(256) void k_scan_apply(const int* __restrict__ cnt, const int* __restrict__ bsum,
                                                    int* __restrict__ row_ptr, int* __restrict__ cursor,
                                                    float* __restrict__ dinv) {
    __shared__ int s[256];
    int tid = threadIdx.x;
    int i = blockIdx.x * 256 + tid;
    int v = (i < NN) ? cnt[i] : 0;
    s[tid] = v;
    __syncthreads();
    for (int o = 1; o < 256; o <<= 1) {
        int t = (tid >= o) ? s[tid - o] : 0;
        __syncthreads();
        s[tid] += t;
        __syncthreads();
    }
    if (i < NN) {
        int p = bsum[blockIdx.x] + s[tid] - v;  // exclusive prefix
        row_ptr[i] = p;
        cursor[i] = p;
        dinv[i] = rsqrtf(1.0f + (float)v);      // deg includes self-loop, always > 0
    }
    if (i == NN - 1) row_ptr[NN] = NE;
}

__global__ __launch_bounds__(256) void k_scatter(const int* __restrict__ src, const int* __restrict__ dst,
                                                 int* __restrict__ cursor, int* __restrict__ col) {
    int e = blockIdx.x * 256 + threadIdx.x;
    if (e < NE) {
        int p = atomicAdd(&cursor[dst[e]], 1);
        col[p] = src[e];
    }
}

// ---------------- GEMM: G[i,:] = dinv[i] * (X @ W)[i,:] ----------------
// Tile: 32 rows x 64 cols per block. 256 threads: tx=tid&15 (col4), ty=tid>>4 (2 rows each).
// LDS: Ws 128x64 f32 = 32KB, xs 32x132 f32 (padded) ~16.5KB.

__device__ inline void fma4(float4& a, float s, const float4& w) {
    a.x = fmaf(s, w.x, a.x);
    a.y = fmaf(s, w.y, a.y);
    a.z = fmaf(s, w.z, a.z);
    a.w = fmaf(s, w.w, a.w);
}

__global__ __launch_bounds__(256) void k_gemm(const float* __restrict__ X, const float* __restrict__ W,
                                              const float* __restrict__ dinv, float* __restrict__ G) {
    __shared__ float Ws[DD * 64];        // Ws[k][c] for c in [c0, c0+64)
    __shared__ float xs[32 * 132];       // padded rows (132) to dodge bank conflicts

    const int tid  = threadIdx.x;
    const int row0 = blockIdx.x * 32;
    const int c0   = blockIdx.y * 64;

    // stage W columns [c0, c0+64): 128 rows x 16 float4
    {
        const float4* W4  = (const float4*)W;
        float4*       Ws4 = (float4*)Ws;
        #pragma unroll
        for (int j = 0; j < 8; ++j) {
            int idx = tid + j * 256;       // 0..2047
            int kk = idx >> 4;             // 0..127
            int cc = idx & 15;             // 0..15
            Ws4[idx] = W4[kk * 32 + (c0 >> 2) + cc];
        }
    }
    // stage X rows [row0, row0+32): contiguous 32x128 block, zero-pad past N
    {
        const float4* X4 = (const float4*)(X + (size_t)row0 * DD);
        int nrows  = NN - row0; if (nrows > 32) nrows = 32;
        int limit4 = (nrows * DD) >> 2;
        #pragma unroll
        for (int j = 0; j < 4; ++j) {
            int idx = tid + j * 256;       // 0..1023
            float4 v;
            if (idx < limit4) v = X4[idx];
            else { v.x = 0.f; v.y = 0.f; v.z = 0.f; v.w = 0.f; }
            int r = idx >> 5, c = idx & 31;
            ((float4*)xs)[r * 33 + c] = v;
        }
    }
    __syncthreads();

    const int tx = tid & 15;    // col group (4 cols)
    const int ty = tid >> 4;    // row pair
    float4 acc0 = {0.f, 0.f, 0.f, 0.f};
    float4 acc1 = {0.f, 0.f, 0.f, 0.f};

    #pragma unroll 4
    for (int k = 0; k < DD; k += 4) {
        float4 w0 = *(const float4*)&Ws[(k + 0) * 64 + tx * 4];
        float4 w1 = *(const float4*)&Ws[(k + 1) * 64 + tx * 4];
        float4 w2 = *(const float4*)&Ws[(k + 2) * 64 + tx * 4];
        float4 w3 = *(const float4*)&Ws[(k + 3) * 64 + tx * 4];
        float4 xv0 = *(const float4*)&xs[(ty * 2 + 0) * 132 + k];
        float4 xv1 = *(const float4*)&xs[(ty * 2 + 1) * 132 + k];
        fma4(acc0, xv0.x, w0); fma4(acc0, xv0.y, w1); fma4(acc0, xv0.z, w2); fma4(acc0, xv0.w, w3);
        fma4(acc1, xv1.x, w0); fma4(acc1, xv1.y, w1); fma4(acc1, xv1.z, w2); fma4(acc1, xv1.w, w3);
    }

    int row = row0 + ty * 2;
    if (row < NN) {
        float di = dinv[row];
        float4 v = {acc0.x * di, acc0.y * di, acc0.z * di, acc0.w * di};
        *(float4*)&G[(size_t)row * DD + c0 + tx * 4] = v;
    }
    if (row + 1 < NN) {
        float di = dinv[row + 1];
        float4 v = {acc1.x * di, acc1.y * di, acc1.z * di, acc1.w * di};
        *(float4*)&G[(size_t)(row + 1) * DD + c0 + tx * 4] = v;
    }
}

// ---------------- Aggregation: H[i] = relu(dinv[i]*(G[i] + sum_{p} G[col[p]]) + b) ----------------
// One wave per node; lane handles 2 features (float2). 4 nodes per 256-thread block.

__global__ __launch_bounds__(256) void k_aggregate(const float* __restrict__ G, const float* __restrict__ dinv,
                                                   const int* __restrict__ row_ptr, const int* __restrict__ col,
                                                   const float* __restrict__ bias, float* __restrict__ H) {
    int node = blockIdx.x * 4 + (threadIdx.x >> 6);
    if (node >= NN) return;
    int lane = threadIdx.x & 63;

    int beg = row_ptr[node];
    int end = row_ptr[node + 1];

    float2 acc = ((const float2*)(G + (size_t)node * DD))[lane];  // self-loop term
    int p = beg;
    for (; p + 1 < end; p += 2) {
        int s0 = col[p], s1 = col[p + 1];
        float2 g0 = ((const float2*)(G + (size_t)s0 * DD))[lane];
        float2 g1 = ((const float2*)(G + (size_t)s1 * DD))[lane];
        acc.x += g0.x + g1.x;
        acc.y += g0.y + g1.y;
    }
    if (p < end) {
        int s0 = col[p];
        float2 g0 = ((const float2*)(G + (size_t)s0 * DD))[lane];
        acc.x += g0.x;
        acc.y += g0.y;
    }

    float di = dinv[node];
    float2 bv = ((const float2*)bias)[lane];
    float2 hv;
    hv.x = fmaxf(fmaf(di, acc.x, bv.x), 0.f);
    hv.y = fmaxf(fmaf(di, acc.y, bv.y), 0.f);
    ((float2*)(H + (size_t)node * DD))[lane] = hv;
}

// ---------------- Layer-2 aggregation fused with both linear heads ----------------

__global__ __launch_bounds__(256) void k_aggregate_heads(const float* __restrict__ G, const float* __restrict__ dinv,
                                                         const int* __restrict__ row_ptr, const int* __restrict__ col,
                                                         const float* __restrict__ bias,
                                                         const float* __restrict__ Wt, const float* __restrict__ bt,
                                                         const float* __restrict__ We, const float* __restrict__ be,
                                                         float* __restrict__ out) {
    int node = blockIdx.x * 4 + (threadIdx.x >> 6);
    if (node >= NN) return;
    int lane = threadIdx.x & 63;

    int beg = row_ptr[node];
    int end = row_ptr[node + 1];

    float2 acc = ((const float2*)(G + (size_t)node * DD))[lane];
    int p = beg;
    for (; p + 1 < end; p += 2) {
        int s0 = col[p], s1 = col[p + 1];
        float2 g0 = ((const float2*)(G + (size_t)s0 * DD))[lane];
        float2 g1 = ((const float2*)(G + (size_t)s1 * DD))[lane];
        acc.x += g0.x + g1.x;
        acc.y += g0.y + g1.y;
    }
    if (p < end) {
        int s0 = col[p];
        float2 g0 = ((const float2*)(G + (size_t)s0 * DD))[lane];
        acc.x += g0.x;
        acc.y += g0.y;
    }

    float di = dinv[node];
    float2 bv = ((const float2*)bias)[lane];
    float hx = fmaxf(fmaf(di, acc.x, bv.x), 0.f);
    float hy = fmaxf(fmaf(di, acc.y, bv.y), 0.f);

    float2 wt = ((const float2*)Wt)[lane];
    float2 we = ((const float2*)We)[lane];
    float t  = hx * wt.x + hy * wt.y;
    float ev = hx * we.x + hy * we.y;
    #pragma unroll
    for (int o = 32; o > 0; o >>= 1) {
        t  += __shfl_down(t, o, 64);
        ev += __shfl_down(ev, o, 64);
    }
    if (lane == 0) {
        out[node]      = t + bt[0];
        out[NN + node] = ev + be[0];
    }
}

// ---------------- launch ----------------

extern "C" void kernel_launch(void* const* d_in, const int* in_sizes, int n_in,
                              void* d_out, int out_size, void* d_ws, size_t ws_size,
                              hipStream_t stream) {
    const float* x  = (const float*)d_in[0];
    const int*   ei = (const int*)d_in[1];
    const float* W1 = (const float*)d_in[2];
    const float* b1 = (const float*)d_in[3];
    const float* W2 = (const float*)d_in[4];
    const float* b2 = (const float*)d_in[5];
    const float* Wt = (const float*)d_in[6];
    const float* bt = (const float*)d_in[7];
    const float* We = (const float*)d_in[8];
    const float* be = (const float*)d_in[9];
    float* out = (float*)d_out;

    const int* srcI = ei;        // edge_index[0]
    const int* dstI = ei + NE;   // edge_index[1]

    char* w = (char*)d_ws;
    float* bufA   = (float*)w;  w += (size_t)NN * DD * sizeof(float);   // 25.6 MB
    float* bufB   = (float*)w;  w += (size_t)NN * DD * sizeof(float);   // 25.6 MB
    float* dinv   = (float*)w;  w += (size_t)NN * sizeof(float);
    int*   cnt    = (int*)w;    w += (size_t)NN * sizeof(int);
    int*   rowp   = (int*)w;    w += (size_t)(NN + 1) * sizeof(int);
    int*   cursor = (int*)w;    w += (size_t)NN * sizeof(int);
    int*   col    = (int*)w;    w += (size_t)NE * sizeof(int);
    int*   bsum   = (int*)w;    w += 256 * sizeof(int);

    const int SCAN_B = (NN + 255) / 256;         // 196
    const int EDGE_B = (NE + 255) / 256;         // 3125
    const int AGG_B  = (NN + 3) / 4;             // 12500
    dim3 gemm_grid((NN + 31) / 32, 2);           // 1563 x 2 col tiles

    hipLaunchKernelGGL(k_init,       dim3(SCAN_B), dim3(256), 0, stream, cnt);
    hipLaunchKernelGGL(k_count,      dim3(EDGE_B), dim3(256), 0, stream, dstI, cnt);
    hipLaunchKernelGGL(k_scan_block, dim3(SCAN_B), dim3(256), 0, stream, cnt, bsum);
    hipLaunchKernelGGL(k_scan_top,   dim3(1),      dim3(256), 0, stream, bsum, SCAN_B);
    hipLaunchKernelGGL(k_scan_apply, dim3(SCAN_B), dim3(256), 0, stream, cnt, bsum, rowp, cursor, dinv);
    hipLaunchKernelGGL(k_scatter,    dim3(EDGE_B), dim3(256), 0, stream, srcI, dstI, cursor, col);

    // layer 1: G1 = dinv * (x @ W1)  -> bufA ; H1 = relu(dinv*agg + b1) -> bufB
    hipLaunchKernelGGL(k_gemm,      gemm_grid,   dim3(256), 0, stream, x, W1, dinv, bufA);
    hipLaunchKernelGGL(k_aggregate, dim3(AGG_B), dim3(256), 0, stream, bufA, dinv, rowp, col, b1, bufB);

    // layer 2: G2 = dinv * (H1 @ W2) -> bufA ; fused aggregation + heads -> out
    hipLaunchKernelGGL(k_gemm,            gemm_grid,   dim3(256), 0, stream, bufB, W2, dinv, bufA);
    hipLaunchKernelGGL(k_aggregate_heads, dim3(AGG_B), dim3(256), 0, stream, bufA, dinv, rowp, col, b2,
                       Wt, bt, We, be, out);
}

// Round 2
// 322.982 us; speedup vs baseline: 1.1294x; 1.1294x over previous
//
#include <hip/hip_runtime.h>
#include <hip/hip_fp16.h>
#include <math.h>

#define NN 50000
#define NE 800000
#define DD 128

// ---------------- CSR build ----------------

__global__ __launch_bounds__(256) void k_init(int* __restrict__ cnt) {
    int i = blockIdx.x * 256 + threadIdx.x;
    if (i < NN) cnt[i] = 0;
}

__global__ __launch_bounds__(256) void k_count(const int* __restrict__ dst, int* __restrict__ cnt) {
    int e = blockIdx.x * 256 + threadIdx.x;
    if (e < NE) atomicAdd(&cnt[dst[e]], 1);
}

__global__ __launch_bounds__(256) void k_scan_block(const int* __restrict__ cnt, int* __restrict__ bsum) {
    __shared__ int s[256];
    int tid = threadIdx.x;
    int i = blockIdx.x * 256 + tid;
    int v = (i < NN) ? cnt[i] : 0;
    s[tid] = v;
    __syncthreads();
    for (int o = 128; o > 0; o >>= 1) {
        if (tid < o) s[tid] += s[tid + o];
        __syncthreads();
    }
    if (tid == 0) bsum[blockIdx.x] = s[0];
}

__global__ __launch_bounds__(256) void k_scan_top(int* __restrict__ bsum, int nb) {
    __shared__ int s[256];
    int tid = threadIdx.x;
    int v = (tid < nb) ? bsum[tid] : 0;
    s[tid] = v;
    __syncthreads();
    for (int o = 1; o < 256; o <<= 1) {
        int t = (tid >= o) ? s[tid - o] : 0;
        __syncthreads();
        s[tid] += t;
        __syncthreads();
    }
    if (tid < nb) bsum[tid] = s[tid] - v;  // exclusive
}

__global__ __launch_bounds__(256) void k_scan_apply(const int* __restrict__ cnt, const int* __restrict__ bsum,
                                                    int* __restrict__ row_ptr, int* __restrict__ cursor,
                                                    float* __restrict__ dinv) {
    __shared__ int s[256];
    int tid = threadIdx.x;
    int i = blockIdx.x * 256 + tid;
    int v = (i < NN) ? cnt[i] : 0;
    s[tid] = v;
    __syncthreads();
    for (int o = 1; o < 256; o <<= 1) {
        int t = (tid >= o) ? s[tid - o] : 0;
        __syncthreads();
        s[tid] += t;
        __syncthreads();
    }
    if (i < NN) {
        int p = bsum[blockIdx.x] + s[tid] - v;  // exclusive prefix
        row_ptr[i] = p;
        cursor[i] = p;
        dinv[i] = rsqrtf(1.0f + (float)v);      // deg includes self-loop, always > 0
    }
    if (i == NN - 1) row_ptr[NN] = NE;
}

__global__ __launch_bounds__(256) void k_scatter(const int* __restrict__ src, const int* __restrict__ dst,
                                                 int* __restrict__ cursor, int* __restrict__ col) {
    int e = blockIdx.x * 256 + threadIdx.x;
    if (e < NE) {
        int p = atomicAdd(&cursor[dst[e]], 1);
        col[p] = src[e];
    }
}

// ---------------- GEMM: G[i,:] = half( dinv[i] * (X @ W)[i,:] ) ----------------
// Tile: 32 rows x 64 cols per block. 256 threads: tx=tid&15 (col4), ty=tid>>4 (2 rows each).

__device__ inline void fma4(float4& a, float s, const float4& w) {
    a.x = fmaf(s, w.x, a.x);
    a.y = fmaf(s, w.y, a.y);
    a.z = fmaf(s, w.z, a.z);
    a.w = fmaf(s, w.w, a.w);
}

__device__ inline void store_half4(__half* p, float4 v) {
    __half2 h01 = __floats2half2_rn(v.x, v.y);
    __half2 h23 = __floats2half2_rn(v.z, v.w);
    uint2 pk;
    pk.x = *(unsigned int*)&h01;
    pk.y = *(unsigned int*)&h23;
    *(uint2*)p = pk;
}

__global__ __launch_bounds__(256) void k_gemm(const float* __restrict__ X, const float* __restrict__ W,
                                              const float* __restrict__ dinv, __half* __restrict__ G) {
    __shared__ float Ws[DD * 64];        // Ws[k][c] for c in [c0, c0+64)
    __shared__ float xs[32 * 132];       // padded rows to dodge bank conflicts

    const int tid  = threadIdx.x;
    const int row0 = blockIdx.x * 32;
    const int c0   = blockIdx.y * 64;

    // stage W columns [c0, c0+64)
    {
        const float4* W4  = (const float4*)W;
        float4*       Ws4 = (float4*)Ws;
        #pragma unroll
        for (int j = 0; j < 8; ++j) {
            int idx = tid + j * 256;       // 0..2047
            int kk = idx >> 4;             // 0..127
            int cc = idx & 15;             // 0..15
            Ws4[idx] = W4[kk * 32 + (c0 >> 2) + cc];
        }
    }
    // stage X rows [row0, row0+32)
    {
        const float4* X4 = (const float4*)(X + (size_t)row0 * DD);
        int nrows  = NN - row0; if (nrows > 32) nrows = 32;
        int limit4 = (nrows * DD) >> 2;
        #pragma unroll
        for (int j = 0; j < 4; ++j) {
            int idx = tid + j * 256;       // 0..1023
            float4 v;
            if (idx < limit4) v = X4[idx];
            else { v.x = 0.f; v.y = 0.f; v.z = 0.f; v.w = 0.f; }
            int r = idx >> 5, c = idx & 31;
            ((float4*)xs)[r * 33 + c] = v;
        }
    }
    __syncthreads();

    const int tx = tid & 15;    // col group (4 cols)
    const int ty = tid >> 4;    // row pair
    float4 acc0 = {0.f, 0.f, 0.f, 0.f};
    float4 acc1 = {0.f, 0.f, 0.f, 0.f};

    #pragma unroll 4
    for (int k = 0; k < DD; k += 4) {
        float4 w0 = *(const float4*)&Ws[(k + 0) * 64 + tx * 4];
        float4 w1 = *(const float4*)&Ws[(k + 1) * 64 + tx * 4];
        float4 w2 = *(const float4*)&Ws[(k + 2) * 64 + tx * 4];
        float4 w3 = *(const float4*)&Ws[(k + 3) * 64 + tx * 4];
        float4 xv0 = *(const float4*)&xs[(ty * 2 + 0) * 132 + k];
        float4 xv1 = *(const float4*)&xs[(ty * 2 + 1) * 132 + k];
        fma4(acc0, xv0.x, w0); fma4(acc0, xv0.y, w1); fma4(acc0, xv0.z, w2); fma4(acc0, xv0.w, w3);
        fma4(acc1, xv1.x, w0); fma4(acc1, xv1.y, w1); fma4(acc1, xv1.z, w2); fma4(acc1, xv1.w, w3);
    }

    int row = row0 + ty * 2;
    if (row < NN) {
        float di = dinv[row];
        float4 v = {acc0.x * di, acc0.y * di, acc0.z * di, acc0.w * di};
        store_half4(&G[(size_t)row * DD + c0 + tx * 4], v);
    }
    if (row + 1 < NN) {
        float di = dinv[row + 1];
        float4 v = {acc1.x * di, acc1.y * di, acc1.z * di, acc1.w * di};
        store_half4(&G[(size_t)(row + 1) * DD + c0 + tx * 4], v);
    }
}

// ---------------- Aggregation: H[i] = relu(dinv[i]*(G[i] + sum_{p} G[col[p]]) + b) ----------------
// One wave per node; lane handles 2 features (half2 load, fp32 accumulate).
// Unroll x4 with two accumulators for more outstanding loads.

__device__ inline float2 gather_node(const __half2* __restrict__ G2, int node, int lane,
                                     const int* __restrict__ col, int beg, int end) {
    float2 sh = __half22float2(G2[(size_t)node * 64 + lane]);   // self-loop term
    float2 accA = sh;
    float2 accB = {0.f, 0.f};
    int p = beg;
    for (; p + 3 < end; p += 4) {
        int s0 = col[p], s1 = col[p + 1], s2 = col[p + 2], s3 = col[p + 3];
        float2 g0 = __half22float2(G2[(size_t)s0 * 64 + lane]);
        float2 g1 = __half22float2(G2[(size_t)s1 * 64 + lane]);
        float2 g2 = __half22float2(G2[(size_t)s2 * 64 + lane]);
        float2 g3 = __half22float2(G2[(size_t)s3 * 64 + lane]);
        accA.x += g0.x + g1.x;  accA.y += g0.y + g1.y;
        accB.x += g2.x + g3.x;  accB.y += g2.y + g3.y;
    }
    for (; p < end; ++p) {
        int s0 = col[p];
        float2 g0 = __half22float2(G2[(size_t)s0 * 64 + lane]);
        accA.x += g0.x;  accA.y += g0.y;
    }
    float2 acc = {accA.x + accB.x, accA.y + accB.y};
    return acc;
}

__global__ __launch_bounds__(256) void k_aggregate(const __half* __restrict__ G, const float* __restrict__ dinv,
                                                   const int* __restrict__ row_ptr, const int* __restrict__ col,
                                                   const float* __restrict__ bias, float* __restrict__ H) {
    int node = blockIdx.x * 4 + (threadIdx.x >> 6);
    if (node >= NN) return;
    int lane = threadIdx.x & 63;

    int beg = row_ptr[node];
    int end = row_ptr[node + 1];
    float2 acc = gather_node((const __half2*)G, node, lane, col, beg, end);

    float di = dinv[node];
    float2 bv = ((const float2*)bias)[lane];
    float2 hv;
    hv.x = fmaxf(fmaf(di, acc.x, bv.x), 0.f);
    hv.y = fmaxf(fmaf(di, acc.y, bv.y), 0.f);
    ((float2*)(H + (size_t)node * DD))[lane] = hv;
}

// ---------------- Layer-2 aggregation fused with both linear heads ----------------

__global__ __launch_bounds__(256) void k_aggregate_heads(const __half* __restrict__ G, const float* __restrict__ dinv,
                                                         const int* __restrict__ row_ptr, const int* __restrict__ col,
                                                         const float* __restrict__ bias,
                                                         const float* __restrict__ Wt, const float* __restrict__ bt,
                                                         const float* __restrict__ We, const float* __restrict__ be,
                                                         float* __restrict__ out) {
    int node = blockIdx.x * 4 + (threadIdx.x >> 6);
    if (node >= NN) return;
    int lane = threadIdx.x & 63;

    int beg = row_ptr[node];
    int end = row_ptr[node + 1];
    float2 acc = gather_node((const __half2*)G, node, lane, col, beg, end);

    float di = dinv[node];
    float2 bv = ((const float2*)bias)[lane];
    float hx = fmaxf(fmaf(di, acc.x, bv.x), 0.f);
    float hy = fmaxf(fmaf(di, acc.y, bv.y), 0.f);

    float2 wt = ((const float2*)Wt)[lane];
    float2 we = ((const float2*)We)[lane];
    float t  = hx * wt.x + hy * wt.y;
    float ev = hx * we.x + hy * we.y;
    #pragma unroll
    for (int o = 32; o > 0; o >>= 1) {
        t  += __shfl_down(t, o, 64);
        ev += __shfl_down(ev, o, 64);
    }
    if (lane == 0) {
        out[node]      = t + bt[0];
        out[NN + node] = ev + be[0];
    }
}

// ---------------- launch ----------------

extern "C" void kernel_launch(void* const* d_in, const int* in_sizes, int n_in,
                              void* d_out, int out_size, void* d_ws, size_t ws_size,
                              hipStream_t stream) {
    const float* x  = (const float*)d_in[0];
    const int*   ei = (const int*)d_in[1];
    const float* W1 = (const float*)d_in[2];
    const float* b1 = (const float*)d_in[3];
    const float* W2 = (const float*)d_in[4];
    const float* b2 = (const float*)d_in[5];
    const float* Wt = (const float*)d_in[6];
    const float* bt = (const float*)d_in[7];
    const float* We = (const float*)d_in[8];
    const float* be = (const float*)d_in[9];
    float* out = (float*)d_out;

    const int* srcI = ei;        // edge_index[0]
    const int* dstI = ei + NE;   // edge_index[1]

    char* w = (char*)d_ws;
    __half* Gh    = (__half*)w; w += (size_t)NN * DD * sizeof(__half);  // 12.8 MB
    float* bufB   = (float*)w;  w += (size_t)NN * DD * sizeof(float);   // 25.6 MB (H1)
    float* dinv   = (float*)w;  w += (size_t)NN * sizeof(float);
    int*   cnt    = (int*)w;    w += (size_t)NN * sizeof(int);
    int*   rowp   = (int*)w;    w += (size_t)(NN + 1) * sizeof(int);
    int*   cursor = (int*)w;    w += (size_t)NN * sizeof(int);
    int*   col    = (int*)w;    w += (size_t)NE * sizeof(int);
    int*   bsum   = (int*)w;    w += 256 * sizeof(int);

    const int SCAN_B = (NN + 255) / 256;         // 196
    const int EDGE_B = (NE + 255) / 256;         // 3125
    const int AGG_B  = (NN + 3) / 4;             // 12500
    dim3 gemm_grid((NN + 31) / 32, 2);           // 1563 x 2 col tiles

    hipLaunchKernelGGL(k_init,       dim3(SCAN_B), dim3(256), 0, stream, cnt);
    hipLaunchKernelGGL(k_count,      dim3(EDGE_B), dim3(256), 0, stream, dstI, cnt);
    hipLaunchKernelGGL(k_scan_block, dim3(SCAN_B), dim3(256), 0, stream, cnt, bsum);
    hipLaunchKernelGGL(k_scan_top,   dim3(1),      dim3(256), 0, stream, bsum, SCAN_B);
    hipLaunchKernelGGL(k_scan_apply, dim3(SCAN_B), dim3(256), 0, stream, cnt, bsum, rowp, cursor, dinv);
    hipLaunchKernelGGL(k_scatter,    dim3(EDGE_B), dim3(256), 0, stream, srcI, dstI, cursor, col);

    // layer 1: G1 = half(dinv * (x @ W1)) -> Gh ; H1 = relu(dinv*agg + b1) -> bufB
    hipLaunchKernelGGL(k_gemm,      gemm_grid,   dim3(256), 0, stream, x, W1, dinv, Gh);
    hipLaunchKernelGGL(k_aggregate, dim3(AGG_B), dim3(256), 0, stream, Gh, dinv, rowp, col, b1, bufB);

    // layer 2: G2 = half(dinv * (H1 @ W2)) -> Gh ; fused aggregation + heads -> out
    hipLaunchKernelGGL(k_gemm,            gemm_grid,   dim3(256), 0, stream, bufB, W2, dinv, Gh);
    hipLaunchKernelGGL(k_aggregate_heads, dim3(AGG_B), dim3(256), 0, stream, Gh, dinv, rowp, col, b2,
                       Wt, bt, We, be, out);
}

// Round 3
// 248.431 us; speedup vs baseline: 1.4683x; 1.3001x over previous
//
#include <hip/hip_runtime.h>
#include <hip/hip_fp16.h>
#include <math.h>

#define NN 50000
#define NE 800000
#define DD 128

#define NB  196      // buckets of 256 nodes (dst >> 8)
#define CAP 5300     // per-bucket segment capacity (mean 4082, sd 64 -> +19 sigma)
#define EPB 4096     // edges per phase-A block

// ---------------- CSR build: bucketed two-phase (coalesced writes) ----------------

__global__ __launch_bounds__(256) void k_init_bcur(int* __restrict__ bcur) {
    int t = threadIdx.x;
    if (t < NB) bcur[t] = t * CAP;
}

// Phase A: bin edges into NB bucket segments; packed = src | (dst&255)<<16
__global__ __launch_bounds__(256) void k_phaseA(const int* __restrict__ src, const int* __restrict__ dst,
                                                int* __restrict__ bcur, unsigned int* __restrict__ ebuf) {
    __shared__ int hist[256];
    __shared__ int scanbuf[256];
    __shared__ int gbase[256];
    __shared__ unsigned int stage[EPB];
    __shared__ int tgt[EPB];

    const int tid = threadIdx.x;
    const int e0  = blockIdx.x * EPB;
    int nE = NE - e0; if (nE > EPB) nE = EPB;

    hist[tid] = 0;
    __syncthreads();

    unsigned int pk[16];
    unsigned int br[16];   // bucket(8b) | rank<<8
    #pragma unroll
    for (int j = 0; j < 16; ++j) {
        int idx = tid + j * 256;
        if (idx < nE) {
            int e = e0 + idx;
            int s = src[e], d = dst[e];
            int b = d >> 8;
            int r = atomicAdd(&hist[b], 1);
            pk[j] = (unsigned int)s | ((unsigned int)(d & 255) << 16);
            br[j] = (unsigned int)b | ((unsigned int)r << 8);
        }
    }
    __syncthreads();
    // inclusive scan of per-bucket counts
    int v = hist[tid];
    scanbuf[tid] = v;
    __syncthreads();
    for (int o = 1; o < 256; o <<= 1) {
        int t2 = (tid >= o) ? scanbuf[tid - o] : 0;
        __syncthreads();
        scanbuf[tid] += t2;
        __syncthreads();
    }
    int base_excl = scanbuf[tid] - v;
    if (tid < NB && v > 0) gbase[tid] = atomicAdd(&bcur[tid], v);
    hist[tid] = base_excl;   // reuse as in-block bucket base
    __syncthreads();

    #pragma unroll
    for (int j = 0; j < 16; ++j) {
        int idx = tid + j * 256;
        if (idx < nE) {
            int b = br[j] & 255;
            int r = (int)(br[j] >> 8);
            int pos = hist[b] + r;
            stage[pos] = pk[j];
            tgt[pos]   = gbase[b] + r;
        }
    }
    __syncthreads();
    #pragma unroll
    for (int j = 0; j < 16; ++j) {
        int idx = tid + j * 256;
        if (idx < nE) ebuf[tgt[idx]] = stage[idx];   // bucket-contiguous runs
    }
}

// scan bucket sizes -> global row base per bucket (bucket-major == node-major)
__global__ __launch_bounds__(256) void k_bucket_scan(const int* __restrict__ bcur, int* __restrict__ bbase,
                                                     int* __restrict__ row_ptr) {
    __shared__ int s[256];
    int tid = threadIdx.x;
    int sz = (tid < NB) ? (bcur[tid] - tid * CAP) : 0;
    s[tid] = sz;
    __syncthreads();
    for (int o = 1; o < 256; o <<= 1) {
        int t = (tid >= o) ? s[tid - o] : 0;
        __syncthreads();
        s[tid] += t;
        __syncthreads();
    }
    if (tid < NB) bbase[tid] = s[tid] - sz;
    if (tid == 0) row_ptr[NN] = NE;
}

// Phase B: per-bucket local CSR; coalesced ushort col flush; row_ptr + dinv
__global__ __launch_bounds__(256) void k_build_csr(const unsigned int* __restrict__ ebuf,
                                                   const int* __restrict__ bcur,
                                                   const int* __restrict__ bbase,
                                                   int* __restrict__ row_ptr,
                                                   float* __restrict__ dinv,
                                                   unsigned short* __restrict__ col) {
    __shared__ int cnt[256];
    __shared__ int scanb[256];
    __shared__ unsigned short stage[CAP];

    const int b   = blockIdx.x;
    const int tid = threadIdx.x;
    const int seg0 = b * CAP;
    const int sb   = bcur[b] - seg0;
    const int n0   = b << 8;
    int nb = NN - n0; if (nb > 256) nb = 256;

    cnt[tid] = 0;
    __syncthreads();
    for (int p = tid; p < sb; p += 256) {
        unsigned int e = ebuf[seg0 + p];
        atomicAdd(&cnt[(e >> 16) & 255], 1);
    }
    __syncthreads();
    int v = cnt[tid];
    scanb[tid] = v;
    __syncthreads();
    for (int o = 1; o < 256; o <<= 1) {
        int t = (tid >= o) ? scanb[tid - o] : 0;
        __syncthreads();
        scanb[tid] += t;
        __syncthreads();
    }
    int excl = scanb[tid] - v;
    const int rbase = bbase[b];
    if (tid < nb) {
        row_ptr[n0 + tid] = rbase + excl;
        dinv[n0 + tid] = rsqrtf(1.0f + (float)v);   // deg incl. self-loop
    }
    cnt[tid] = excl;    // reuse as cursor
    __syncthreads();
    for (int p = tid; p < sb; p += 256) {
        unsigned int e = ebuf[seg0 + p];
        int pos = atomicAdd(&cnt[(e >> 16) & 255], 1);
        stage[pos] = (unsigned short)(e & 0xFFFFu);
    }
    __syncthreads();
    for (int p = tid; p < sb; p += 256) {
        col[rbase + p] = stage[p];                  // coalesced
    }
}

// ---------------- GEMM: G[i,:] = half( dinv[i] * (X @ W)[i,:] ) ----------------

__device__ inline void fma4(float4& a, float s, const float4& w) {
    a.x = fmaf(s, w.x, a.x);
    a.y = fmaf(s, w.y, a.y);
    a.z = fmaf(s, w.z, a.z);
    a.w = fmaf(s, w.w, a.w);
}

__device__ inline void store_half4(__half* p, float4 v) {
    __half2 h01 = __floats2half2_rn(v.x, v.y);
    __half2 h23 = __floats2half2_rn(v.z, v.w);
    uint2 pk;
    pk.x = *(unsigned int*)&h01;
    pk.y = *(unsigned int*)&h23;
    *(uint2*)p = pk;
}

__global__ __launch_bounds__(256) void k_gemm(const float* __restrict__ X, const float* __restrict__ W,
                                              const float* __restrict__ dinv, __half* __restrict__ G) {
    __shared__ float Ws[DD * 64];
    __shared__ float xs[32 * 132];

    const int tid  = threadIdx.x;
    const int row0 = blockIdx.x * 32;
    const int c0   = blockIdx.y * 64;

    {
        const float4* W4  = (const float4*)W;
        float4*       Ws4 = (float4*)Ws;
        #pragma unroll
        for (int j = 0; j < 8; ++j) {
            int idx = tid + j * 256;
            int kk = idx >> 4;
            int cc = idx & 15;
            Ws4[idx] = W4[kk * 32 + (c0 >> 2) + cc];
        }
    }
    {
        const float4* X4 = (const float4*)(X + (size_t)row0 * DD);
        int nrows  = NN - row0; if (nrows > 32) nrows = 32;
        int limit4 = (nrows * DD) >> 2;
        #pragma unroll
        for (int j = 0; j < 4; ++j) {
            int idx = tid + j * 256;
            float4 v;
            if (idx < limit4) v = X4[idx];
            else { v.x = 0.f; v.y = 0.f; v.z = 0.f; v.w = 0.f; }
            int r = idx >> 5, c = idx & 31;
            ((float4*)xs)[r * 33 + c] = v;
        }
    }
    __syncthreads();

    const int tx = tid & 15;
    const int ty = tid >> 4;
    float4 acc0 = {0.f, 0.f, 0.f, 0.f};
    float4 acc1 = {0.f, 0.f, 0.f, 0.f};

    #pragma unroll 4
    for (int k = 0; k < DD; k += 4) {
        float4 w0 = *(const float4*)&Ws[(k + 0) * 64 + tx * 4];
        float4 w1 = *(const float4*)&Ws[(k + 1) * 64 + tx * 4];
        float4 w2 = *(const float4*)&Ws[(k + 2) * 64 + tx * 4];
        float4 w3 = *(const float4*)&Ws[(k + 3) * 64 + tx * 4];
        float4 xv0 = *(const float4*)&xs[(ty * 2 + 0) * 132 + k];
        float4 xv1 = *(const float4*)&xs[(ty * 2 + 1) * 132 + k];
        fma4(acc0, xv0.x, w0); fma4(acc0, xv0.y, w1); fma4(acc0, xv0.z, w2); fma4(acc0, xv0.w, w3);
        fma4(acc1, xv1.x, w0); fma4(acc1, xv1.y, w1); fma4(acc1, xv1.z, w2); fma4(acc1, xv1.w, w3);
    }

    int row = row0 + ty * 2;
    if (row < NN) {
        float di = dinv[row];
        float4 v = {acc0.x * di, acc0.y * di, acc0.z * di, acc0.w * di};
        store_half4(&G[(size_t)row * DD + c0 + tx * 4], v);
    }
    if (row + 1 < NN) {
        float di = dinv[row + 1];
        float4 v = {acc1.x * di, acc1.y * di, acc1.z * di, acc1.w * di};
        store_half4(&G[(size_t)(row + 1) * DD + c0 + tx * 4], v);
    }
}

// ---------------- Aggregation ----------------

__device__ inline float2 gather_node(const __half2* __restrict__ G2, int node, int lane,
                                     const unsigned short* __restrict__ col, int beg, int end) {
    float2 accA = __half22float2(G2[(size_t)node * 64 + lane]);   // self-loop term
    float2 accB = {0.f, 0.f};
    int p = beg;
    for (; p + 3 < end; p += 4) {
        int s0 = col[p], s1 = col[p + 1], s2 = col[p + 2], s3 = col[p + 3];
        float2 g0 = __half22float2(G2[(size_t)s0 * 64 + lane]);
        float2 g1 = __half22float2(G2[(size_t)s1 * 64 + lane]);
        float2 g2 = __half22float2(G2[(size_t)s2 * 64 + lane]);
        float2 g3 = __half22float2(G2[(size_t)s3 * 64 + lane]);
        accA.x += g0.x + g1.x;  accA.y += g0.y + g1.y;
        accB.x += g2.x + g3.x;  accB.y += g2.y + g3.y;
    }
    for (; p < end; ++p) {
        int s0 = col[p];
        float2 g0 = __half22float2(G2[(size_t)s0 * 64 + lane]);
        accA.x += g0.x;  accA.y += g0.y;
    }
    float2 acc = {accA.x + accB.x, accA.y + accB.y};
    return acc;
}

__global__ __launch_bounds__(256) void k_aggregate(const __half* __restrict__ G, const float* __restrict__ dinv,
                                                   const int* __restrict__ row_ptr, const unsigned short* __restrict__ col,
                                                   const float* __restrict__ bias, float* __restrict__ H) {
    int node = blockIdx.x * 4 + (threadIdx.x >> 6);
    if (node >= NN) return;
    int lane = threadIdx.x & 63;

    int beg = row_ptr[node];
    int end = row_ptr[node + 1];
    float2 acc = gather_node((const __half2*)G, node, lane, col, beg, end);

    float di = dinv[node];
    float2 bv = ((const float2*)bias)[lane];
    float2 hv;
    hv.x = fmaxf(fmaf(di, acc.x, bv.x), 0.f);
    hv.y = fmaxf(fmaf(di, acc.y, bv.y), 0.f);
    ((float2*)(H + (size_t)node * DD))[lane] = hv;
}

__global__ __launch_bounds__(256) void k_aggregate_heads(const __half* __restrict__ G, const float* __restrict__ dinv,
                                                         const int* __restrict__ row_ptr, const unsigned short* __restrict__ col,
                                                         const float* __restrict__ bias,
                                                         const float* __restrict__ Wt, const float* __restrict__ bt,
                                                         const float* __restrict__ We, const float* __restrict__ be,
                                                         float* __restrict__ out) {
    int node = blockIdx.x * 4 + (threadIdx.x >> 6);
    if (node >= NN) return;
    int lane = threadIdx.x & 63;

    int beg = row_ptr[node];
    int end = row_ptr[node + 1];
    float2 acc = gather_node((const __half2*)G, node, lane, col, beg, end);

    float di = dinv[node];
    float2 bv = ((const float2*)bias)[lane];
    float hx = fmaxf(fmaf(di, acc.x, bv.x), 0.f);
    float hy = fmaxf(fmaf(di, acc.y, bv.y), 0.f);

    float2 wt = ((const float2*)Wt)[lane];
    float2 we = ((const float2*)We)[lane];
    float t  = hx * wt.x + hy * wt.y;
    float ev = hx * we.x + hy * we.y;
    #pragma unroll
    for (int o = 32; o > 0; o >>= 1) {
        t  += __shfl_down(t, o, 64);
        ev += __shfl_down(ev, o, 64);
    }
    if (lane == 0) {
        out[node]      = t + bt[0];
        out[NN + node] = ev + be[0];
    }
}

// ---------------- launch ----------------

extern "C" void kernel_launch(void* const* d_in, const int* in_sizes, int n_in,
                              void* d_out, int out_size, void* d_ws, size_t ws_size,
                              hipStream_t stream) {
    const float* x  = (const float*)d_in[0];
    const int*   ei = (const int*)d_in[1];
    const float* W1 = (const float*)d_in[2];
    const float* b1 = (const float*)d_in[3];
    const float* W2 = (const float*)d_in[4];
    const float* b2 = (const float*)d_in[5];
    const float* Wt = (const float*)d_in[6];
    const float* bt = (const float*)d_in[7];
    const float* We = (const float*)d_in[8];
    const float* be = (const float*)d_in[9];
    float* out = (float*)d_out;

    const int* srcI = ei;        // edge_index[0]
    const int* dstI = ei + NE;   // edge_index[1]

    char* w = (char*)d_ws;
    __half*         Gh    = (__half*)w;         w += (size_t)NN * DD * sizeof(__half);   // 12.8 MB
    float*          bufB  = (float*)w;          w += (size_t)NN * DD * sizeof(float);    // 25.6 MB
    unsigned int*   ebuf  = (unsigned int*)w;   w += (size_t)NB * CAP * sizeof(unsigned int); // 4.15 MB
    unsigned short* col   = (unsigned short*)w; w += (size_t)NE * sizeof(unsigned short);     // 1.6 MB
    float*          dinv  = (float*)w;          w += (size_t)NN * sizeof(float);
    int*            rowp  = (int*)w;            w += (size_t)(NN + 1) * sizeof(int);
    int*            bcur  = (int*)w;            w += (size_t)NB * sizeof(int);
    int*            bbase = (int*)w;            w += (size_t)NB * sizeof(int);

    const int A_B   = (NE + EPB - 1) / EPB;      // 196
    const int AGG_B = (NN + 3) / 4;              // 12500
    dim3 gemm_grid((NN + 31) / 32, 2);

    hipLaunchKernelGGL(k_init_bcur,  dim3(1),    dim3(256), 0, stream, bcur);
    hipLaunchKernelGGL(k_phaseA,     dim3(A_B),  dim3(256), 0, stream, srcI, dstI, bcur, ebuf);
    hipLaunchKernelGGL(k_bucket_scan,dim3(1),    dim3(256), 0, stream, bcur, bbase, rowp);
    hipLaunchKernelGGL(k_build_csr,  dim3(NB),   dim3(256), 0, stream, ebuf, bcur, bbase, rowp, dinv, col);

    // layer 1
    hipLaunchKernelGGL(k_gemm,      gemm_grid,   dim3(256), 0, stream, x, W1, dinv, Gh);
    hipLaunchKernelGGL(k_aggregate, dim3(AGG_B), dim3(256), 0, stream, Gh, dinv, rowp, col, b1, bufB);

    // layer 2 + heads
    hipLaunchKernelGGL(k_gemm,            gemm_grid,   dim3(256), 0, stream, bufB, W2, dinv, Gh);
    hipLaunchKernelGGL(k_aggregate_heads, dim3(AGG_B), dim3(256), 0, stream, Gh, dinv, rowp, col, b2,
                       Wt, bt, We, be, out);
}

// Round 4
// 223.350 us; speedup vs baseline: 1.6332x; 1.1123x over previous
//
#include <hip/hip_runtime.h>
#include <hip/hip_fp16.h>
#include <math.h>

#define NN 50000
#define NE 800000
#define DD 128

#define NB  196      // buckets of 256 nodes (dst >> 8)
#define CAP 5300     // per-bucket segment capacity (mean 4082, sd 64 -> +19 sigma)
#define EPB 4096     // edges per phase-A block

#define CONV_B 6250  // blocks for x->fp16 conversion (6.4M floats / 1024)

typedef _Float16 half8_t __attribute__((ext_vector_type(8)));
typedef float f32x4 __attribute__((ext_vector_type(4)));

// ---------------- CSR build: bucketed two-phase (coalesced writes) ----------------

__global__ __launch_bounds__(256) void k_init_bcur(int* __restrict__ bcur) {
    int t = threadIdx.x;
    if (t < NB) bcur[t] = t * CAP;
}

__global__ __launch_bounds__(256) void k_phaseA(const int* __restrict__ src, const int* __restrict__ dst,
                                                int* __restrict__ bcur, unsigned int* __restrict__ ebuf) {
    __shared__ int hist[256];
    __shared__ int scanbuf[256];
    __shared__ int gbase[256];
    __shared__ unsigned int stage[EPB];
    __shared__ int tgt[EPB];

    const int tid = threadIdx.x;
    const int e0  = blockIdx.x * EPB;
    int nE = NE - e0; if (nE > EPB) nE = EPB;

    hist[tid] = 0;
    __syncthreads();

    unsigned int pk[16];
    unsigned int br[16];   // bucket(8b) | rank<<8
    #pragma unroll
    for (int j = 0; j < 16; ++j) {
        int idx = tid + j * 256;
        if (idx < nE) {
            int e = e0 + idx;
            int s = src[e], d = dst[e];
            int b = d >> 8;
            int r = atomicAdd(&hist[b], 1);
            pk[j] = (unsigned int)s | ((unsigned int)(d & 255) << 16);
            br[j] = (unsigned int)b | ((unsigned int)r << 8);
        }
    }
    __syncthreads();
    int v = hist[tid];
    scanbuf[tid] = v;
    __syncthreads();
    for (int o = 1; o < 256; o <<= 1) {
        int t2 = (tid >= o) ? scanbuf[tid - o] : 0;
        __syncthreads();
        scanbuf[tid] += t2;
        __syncthreads();
    }
    int base_excl = scanbuf[tid] - v;
    if (tid < NB && v > 0) gbase[tid] = atomicAdd(&bcur[tid], v);
    hist[tid] = base_excl;
    __syncthreads();

    #pragma unroll
    for (int j = 0; j < 16; ++j) {
        int idx = tid + j * 256;
        if (idx < nE) {
            int b = br[j] & 255;
            int r = (int)(br[j] >> 8);
            int pos = hist[b] + r;
            stage[pos] = pk[j];
            tgt[pos]   = gbase[b] + r;
        }
    }
    __syncthreads();
    #pragma unroll
    for (int j = 0; j < 16; ++j) {
        int idx = tid + j * 256;
        if (idx < nE) ebuf[tgt[idx]] = stage[idx];
    }
}

__global__ __launch_bounds__(256) void k_bucket_scan(const int* __restrict__ bcur, int* __restrict__ bbase,
                                                     int* __restrict__ row_ptr) {
    __shared__ int s[256];
    int tid = threadIdx.x;
    int sz = (tid < NB) ? (bcur[tid] - tid * CAP) : 0;
    s[tid] = sz;
    __syncthreads();
    for (int o = 1; o < 256; o <<= 1) {
        int t = (tid >= o) ? s[tid - o] : 0;
        __syncthreads();
        s[tid] += t;
        __syncthreads();
    }
    if (tid < NB) bbase[tid] = s[tid] - sz;
    if (tid == 0) row_ptr[NN] = NE;
}

__global__ __launch_bounds__(256) void k_build_csr(const unsigned int* __restrict__ ebuf,
                                                   const int* __restrict__ bcur,
                                                   const int* __restrict__ bbase,
                                                   int* __restrict__ row_ptr,
                                                   float* __restrict__ dinv,
                                                   unsigned short* __restrict__ col) {
    __shared__ int cnt[256];
    __shared__ int scanb[256];
    __shared__ unsigned short stage[CAP];

    const int b   = blockIdx.x;
    const int tid = threadIdx.x;
    const int seg0 = b * CAP;
    const int sb   = bcur[b] - seg0;
    const int n0   = b << 8;
    int nb = NN - n0; if (nb > 256) nb = 256;

    cnt[tid] = 0;
    __syncthreads();
    for (int p = tid; p < sb; p += 256) {
        unsigned int e = ebuf[seg0 + p];
        atomicAdd(&cnt[(e >> 16) & 255], 1);
    }
    __syncthreads();
    int v = cnt[tid];
    scanb[tid] = v;
    __syncthreads();
    for (int o = 1; o < 256; o <<= 1) {
        int t = (tid >= o) ? scanb[tid - o] : 0;
        __syncthreads();
        scanb[tid] += t;
        __syncthreads();
    }
    int excl = scanb[tid] - v;
    const int rbase = bbase[b];
    if (tid < nb) {
        row_ptr[n0 + tid] = rbase + excl;
        dinv[n0 + tid] = rsqrtf(1.0f + (float)v);
    }
    cnt[tid] = excl;
    __syncthreads();
    for (int p = tid; p < sb; p += 256) {
        unsigned int e = ebuf[seg0 + p];
        int pos = atomicAdd(&cnt[(e >> 16) & 255], 1);
        stage[pos] = (unsigned short)(e & 0xFFFFu);
    }
    __syncthreads();
    for (int p = tid; p < sb; p += 256) {
        col[rbase + p] = stage[p];
    }
}

// ---------------- prep: x -> fp16, W1/W2 -> fp16 transposed [n][k] ----------------

__global__ __launch_bounds__(256) void k_prep(const float* __restrict__ x,
                                              const float* __restrict__ W1, const float* __restrict__ W2,
                                              __half* __restrict__ Xh,
                                              __half* __restrict__ WT1, __half* __restrict__ WT2) {
    int b = blockIdx.x;
    int tid = threadIdx.x;
    if (b < CONV_B) {
        int idx = b * 256 + tid;                  // float4 index
        if (idx < (NN * DD) / 4) {
            float4 v = ((const float4*)x)[idx];
            __half2 a = __floats2half2_rn(v.x, v.y);
            __half2 c = __floats2half2_rn(v.z, v.w);
            uint2 pk;
            pk.x = *(unsigned int*)&a;
            pk.y = *(unsigned int*)&c;
            ((uint2*)Xh)[idx] = pk;
        }
    } else {
        const float* W  = (b == CONV_B) ? W1 : W2;
        __half*      WT = (b == CONV_B) ? WT1 : WT2;
        // thread t: n = t>>1, k in [(t&1)*64, +64)
        int n = tid >> 1;
        int k0 = (tid & 1) * 64;
        #pragma unroll 8
        for (int j = 0; j < 64; ++j) {
            int k = k0 + j;
            WT[n * DD + k] = __float2half(W[k * DD + n]);
        }
    }
}

// ---------------- MFMA GEMM: G[i,:] = half( dinv[i] * (Xh @ W)[i,:] ) ----------------
// Block: 256 thr = 4 waves; block computes 64 rows x 128 cols; K = 128.
// LDS: Wl [128][136] half (WT layout [n][k]), Al [64][136] half ([m][k], reused for epilogue).

#define LPAD 136

__global__ __launch_bounds__(256) void k_gemm_mfma(const __half* __restrict__ Xh, const __half* __restrict__ WT,
                                                   const float* __restrict__ dinv, __half* __restrict__ G) {
    __shared__ __half Wl[DD * LPAD];
    __shared__ __half Al[64 * LPAD];

    const int tid  = threadIdx.x;
    const int row0 = blockIdx.x * 64;

    // stage WT (16384 halves): 2048 16B-units, 8 per thread
    {
        const uint4* WTg = (const uint4*)WT;
        #pragma unroll
        for (int j = 0; j < 8; ++j) {
            int u = tid + j * 256;           // 0..2047
            int n = u >> 4, koff = (u & 15) * 8;
            uint4 v = WTg[u];
            *(uint4*)&Wl[n * LPAD + koff] = v;
        }
    }
    // stage X rows [row0, row0+64): 1024 16B-units, 4 per thread
    {
        #pragma unroll
        for (int j = 0; j < 4; ++j) {
            int u = tid + j * 256;           // 0..1023
            int r = u >> 4, koff = (u & 15) * 8;
            uint4 v;
            if (row0 + r < NN) v = *(const uint4*)&Xh[(size_t)(row0 + r) * DD + koff];
            else { v.x = 0; v.y = 0; v.z = 0; v.w = 0; }
            *(uint4*)&Al[r * LPAD + koff] = v;
        }
    }
    __syncthreads();

    const int wave = tid >> 6;
    const int lane = tid & 63;
    const int m    = lane & 15;
    const int quad = lane >> 4;

    f32x4 acc[8];
    #pragma unroll
    for (int t = 0; t < 8; ++t) acc[t] = (f32x4){0.f, 0.f, 0.f, 0.f};

    #pragma unroll
    for (int kk = 0; kk < DD; kk += 32) {
        half8_t a = *(const half8_t*)&Al[(wave * 16 + m) * LPAD + kk + quad * 8];
        #pragma unroll
        for (int t = 0; t < 8; ++t) {
            half8_t b = *(const half8_t*)&Wl[(t * 16 + m) * LPAD + kk + quad * 8];
            acc[t] = __builtin_amdgcn_mfma_f32_16x16x32_f16(a, b, acc[t], 0, 0, 0);
        }
    }

    __syncthreads();   // Al free; reuse for epilogue staging

    // dinv for this lane's 4 rows: rows row0 + wave*16 + quad*4 + r  (16B-aligned, padded alloc)
    float4 dv = *(const float4*)&dinv[row0 + wave * 16 + quad * 4];

    #pragma unroll
    for (int t = 0; t < 8; ++t) {
        #pragma unroll
        for (int r = 0; r < 4; ++r) {
            int row_l = wave * 16 + quad * 4 + r;
            int c     = t * 16 + m;
            float val = acc[t][r] * ((const float*)&dv)[r];
            Al[row_l * LPAD + c] = __float2half(val);
        }
    }
    __syncthreads();

    // coalesced copy out
    {
        #pragma unroll
        for (int j = 0; j < 4; ++j) {
            int u = tid + j * 256;
            int r = u >> 4, koff = (u & 15) * 8;
            if (row0 + r < NN) {
                uint4 v = *(const uint4*)&Al[r * LPAD + koff];
                *(uint4*)&G[(size_t)(row0 + r) * DD + koff] = v;
            }
        }
    }
}

// ---------------- Aggregation (half4/lane, paired edges across wave halves) ----------------

__device__ inline float4 h4_to_f4(uint2 r) {
    __half2 a = *(__half2*)&r.x;
    __half2 b = *(__half2*)&r.y;
    float2 lo = __half22float2(a), hi = __half22float2(b);
    return make_float4(lo.x, lo.y, hi.x, hi.y);
}

__device__ inline uint2 f4_to_h4(float4 v) {
    __half2 a = __floats2half2_rn(v.x, v.y);
    __half2 b = __floats2half2_rn(v.z, v.w);
    uint2 r;
    r.x = *(unsigned int*)&a;
    r.y = *(unsigned int*)&b;
    return r;
}

// returns per-lane partial: features 4*fo .. 4*fo+3 summed over self + all edges,
// after cross-half combine (all 64 lanes hold the full sum for their feature quad)
__device__ inline float4 gather_node4(const __half* __restrict__ G, int node, int lane,
                                      const unsigned short* __restrict__ col, int beg, int end) {
    const int hs = lane >> 5;          // which edge of a pair
    const int fo = lane & 31;          // feature quad
    const size_t foff = (size_t)fo * 4;

    float4 accA, accB = make_float4(0.f, 0.f, 0.f, 0.f);
    {   // self term: low half only
        float4 v = h4_to_f4(*(const uint2*)(G + (size_t)node * DD + foff));
        accA = (hs == 0) ? v : make_float4(0.f, 0.f, 0.f, 0.f);
    }

    int p = beg;
    for (; p + 3 < end; p += 4) {
        int sA = col[p + hs];
        int sB = col[p + 2 + hs];
        float4 vA = h4_to_f4(*(const uint2*)(G + (size_t)sA * DD + foff));
        float4 vB = h4_to_f4(*(const uint2*)(G + (size_t)sB * DD + foff));
        accA.x += vA.x; accA.y += vA.y; accA.z += vA.z; accA.w += vA.w;
        accB.x += vB.x; accB.y += vB.y; accB.z += vB.z; accB.w += vB.w;
    }
    for (; p < end; p += 2) {
        int idx = p + hs;
        bool active = (hs == 0) || (p + 1 < end);
        if (idx >= end) idx = p;
        int s = col[idx];
        float4 v = h4_to_f4(*(const uint2*)(G + (size_t)s * DD + foff));
        if (active) {
            accA.x += v.x; accA.y += v.y; accA.z += v.z; accA.w += v.w;
        }
    }
    accA.x += accB.x; accA.y += accB.y; accA.z += accB.z; accA.w += accB.w;
    accA.x += __shfl_xor(accA.x, 32, 64);
    accA.y += __shfl_xor(accA.y, 32, 64);
    accA.z += __shfl_xor(accA.z, 32, 64);
    accA.w += __shfl_xor(accA.w, 32, 64);
    return accA;
}

__global__ __launch_bounds__(256) void k_aggregate(const __half* __restrict__ G, const float* __restrict__ dinv,
                                                   const int* __restrict__ row_ptr, const unsigned short* __restrict__ col,
                                                   const float* __restrict__ bias, __half* __restrict__ H) {
    int node = blockIdx.x * 4 + (threadIdx.x >> 6);
    if (node >= NN) return;
    int lane = threadIdx.x & 63;

    int beg = row_ptr[node];
    int end = row_ptr[node + 1];
    float4 acc = gather_node4(G, node, lane, col, beg, end);

    float di = dinv[node];
    int fo = lane & 31;
    float4 bv = ((const float4*)bias)[fo];
    float4 hv;
    hv.x = fmaxf(fmaf(di, acc.x, bv.x), 0.f);
    hv.y = fmaxf(fmaf(di, acc.y, bv.y), 0.f);
    hv.z = fmaxf(fmaf(di, acc.z, bv.z), 0.f);
    hv.w = fmaxf(fmaf(di, acc.w, bv.w), 0.f);
    if ((lane >> 5) == 0) {
        *(uint2*)(H + (size_t)node * DD + (size_t)fo * 4) = f4_to_h4(hv);
    }
}

__global__ __launch_bounds__(256) void k_aggregate_heads(const __half* __restrict__ G, const float* __restrict__ dinv,
                                                         const int* __restrict__ row_ptr, const unsigned short* __restrict__ col,
                                                         const float* __restrict__ bias,
                                                         const float* __restrict__ Wt, const float* __restrict__ bt,
                                                         const float* __restrict__ We, const float* __restrict__ be,
                                                         float* __restrict__ out) {
    int node = blockIdx.x * 4 + (threadIdx.x >> 6);
    if (node >= NN) return;
    int lane = threadIdx.x & 63;

    int beg = row_ptr[node];
    int end = row_ptr[node + 1];
    float4 acc = gather_node4(G, node, lane, col, beg, end);

    float di = dinv[node];
    int fo = lane & 31;
    float4 bv = ((const float4*)bias)[fo];
    float hx = fmaxf(fmaf(di, acc.x, bv.x), 0.f);
    float hy = fmaxf(fmaf(di, acc.y, bv.y), 0.f);
    float hz = fmaxf(fmaf(di, acc.z, bv.z), 0.f);
    float hw = fmaxf(fmaf(di, acc.w, bv.w), 0.f);

    float4 wt = ((const float4*)Wt)[fo];
    float4 we = ((const float4*)We)[fo];
    float t  = hx * wt.x + hy * wt.y + hz * wt.z + hw * wt.w;
    float ev = hx * we.x + hy * we.y + hz * we.z + hw * we.w;
    #pragma unroll
    for (int o = 16; o > 0; o >>= 1) {
        t  += __shfl_xor(t, o, 64);
        ev += __shfl_xor(ev, o, 64);
    }
    if (lane == 0) {
        out[node]      = t + bt[0];
        out[NN + node] = ev + be[0];
    }
}

// ---------------- launch ----------------

extern "C" void kernel_launch(void* const* d_in, const int* in_sizes, int n_in,
                              void* d_out, int out_size, void* d_ws, size_t ws_size,
                              hipStream_t stream) {
    const float* x  = (const float*)d_in[0];
    const int*   ei = (const int*)d_in[1];
    const float* W1 = (const float*)d_in[2];
    const float* b1 = (const float*)d_in[3];
    const float* W2 = (const float*)d_in[4];
    const float* b2 = (const float*)d_in[5];
    const float* Wt = (const float*)d_in[6];
    const float* bt = (const float*)d_in[7];
    const float* We = (const float*)d_in[8];
    const float* be = (const float*)d_in[9];
    float* out = (float*)d_out;

    const int* srcI = ei;
    const int* dstI = ei + NE;

    char* w = (char*)d_ws;
    __half*         Xh    = (__half*)w;         w += (size_t)NN * DD * sizeof(__half);        // 12.8 MB
    __half*         Gh    = (__half*)w;         w += (size_t)NN * DD * sizeof(__half);        // 12.8 MB
    __half*         H1h   = (__half*)w;         w += (size_t)NN * DD * sizeof(__half);        // 12.8 MB
    __half*         WT1   = (__half*)w;         w += (size_t)DD * DD * sizeof(__half);        // 32 KB
    __half*         WT2   = (__half*)w;         w += (size_t)DD * DD * sizeof(__half);        // 32 KB
    unsigned int*   ebuf  = (unsigned int*)w;   w += (size_t)NB * CAP * sizeof(unsigned int); // 4.15 MB
    unsigned short* col   = (unsigned short*)w; w += (size_t)NE * sizeof(unsigned short);     // 1.6 MB
    float*          dinv  = (float*)w;          w += (size_t)(NN + 64) * sizeof(float);       // padded
    int*            rowp  = (int*)w;            w += (size_t)(NN + 1) * sizeof(int);
    int*            bcur  = (int*)w;            w += (size_t)NB * sizeof(int);
    int*            bbase = (int*)w;            w += (size_t)NB * sizeof(int);

    const int A_B    = (NE + EPB - 1) / EPB;     // 196
    const int AGG_B  = (NN + 3) / 4;             // 12500
    const int GEMM_B = (NN + 63) / 64;           // 782

    hipLaunchKernelGGL(k_init_bcur,  dim3(1),          dim3(256), 0, stream, bcur);
    hipLaunchKernelGGL(k_phaseA,     dim3(A_B),        dim3(256), 0, stream, srcI, dstI, bcur, ebuf);
    hipLaunchKernelGGL(k_bucket_scan,dim3(1),          dim3(256), 0, stream, bcur, bbase, rowp);
    hipLaunchKernelGGL(k_build_csr,  dim3(NB),         dim3(256), 0, stream, ebuf, bcur, bbase, rowp, dinv, col);
    hipLaunchKernelGGL(k_prep,       dim3(CONV_B + 2), dim3(256), 0, stream, x, W1, W2, Xh, WT1, WT2);

    // layer 1
    hipLaunchKernelGGL(k_gemm_mfma, dim3(GEMM_B), dim3(256), 0, stream, Xh, WT1, dinv, Gh);
    hipLaunchKernelGGL(k_aggregate, dim3(AGG_B),  dim3(256), 0, stream, Gh, dinv, rowp, col, b1, H1h);

    // layer 2 + heads
    hipLaunchKernelGGL(k_gemm_mfma,       dim3(GEMM_B), dim3(256), 0, stream, H1h, WT2, dinv, Gh);
    hipLaunchKernelGGL(k_aggregate_heads, dim3(AGG_B),  dim3(256), 0, stream, Gh, dinv, rowp, col, b2,
                       Wt, bt, We, be, out);
}